// Round 8
// baseline (154.258 us; speedup 1.0000x reference)
//
#include <hip/hip_runtime.h>

// Warp: trilinear grid_sample, padding_mode='zeros', align_corners=true.
// image: (B=2, C=1, H=128, W=128, D=128) fp32
// ddf:   (B=2, 3, H, W, D) fp32 voxel displacements; out: (B,1,H,W,D) fp32
//
// R18 PROBE (resubmit; previous round was an infra failure, no data):
// direct-global gather (no LDS, no barrier). Rationale: image is 16.8
// MB/batch -> fully L3-resident, ~2.6 MB/XCD slab L2-resident under the
// swizzle, so the 8 taps/voxel are cache hits; LDS staging bought banked
// reads at the price of 4-8x image amplification, an fp16 pack phase, and
// the barrier's mandatory vmcnt(0) drain (the R13-R17 ledger shows that
// structure is a hard local optimum at ~102.5-104us). This kernel: zero
// barriers, zero LDS, ~32 scattered dword loads/thread against L1/L2, 32
// independent waves/CU. Mapping (16^3 tiles, XCD slab swizzle, 4-z/thread,
// coalesced fvec4 ddf loads + NT fvec4 out store) identical to R17 -- only
// the tap source changes. All taps use the exact zero-padding formula
// (clamped index + zeroed weight), fp32 end-to-end.
// Revert criterion: dur_us >= 103 -> restore R17, declare ceiling.

constexpr int H = 128, W = 128, D = 128;
constexpr int N = H * W * D;      // 2^21
constexpr int B = 2;

typedef float fvec4 __attribute__((ext_vector_type(4)));

__global__ __launch_bounds__(1024, 8) void warp_gather_kernel(
    const float* __restrict__ image,
    const float* __restrict__ ddf,
    float* __restrict__ out)
{
    // XCD slab swizzle (as R17): XCD k owns tile range [k*128, (k+1)*128)
    // = 2 contiguous x-slabs (~2.6 MB incl. tap reach) -> L2-resident.
    int bid = blockIdx.x;
    int T   = (bid & 7) * 128 + (bid >> 3);
    int b  = T >> 9;              // 512 tiles per batch
    int t3 = T & 511;
    int tx0 = ((t3 >> 6) & 7) << 4;
    int ty0 = ((t3 >> 3) & 7) << 4;
    int tz0 = (t3 & 7) << 4;

    const float* img = image + ((size_t)b << 21);
    int t = threadIdx.x;          // 0..1023

    // thread -> 4 consecutive z voxels (16B-aligned lin0)
    int zq = (t & 3) << 2;        // 0,4,8,12
    int ly = (t >> 2) & 15;
    int lx = t >> 6;
    int vx = tx0 + lx, vy = ty0 + ly, vz = tz0 + zq;
    int lin0 = (vx << 14) + (vy << 7) + vz;

    // ddf: 3 coalesced fvec4 loads (issued first; consumed below --
    // latency hidden by the 32 independent waves/CU, no barrier to drain)
    const float* ddfb = ddf + (size_t)b * 3 * N;
    fvec4 dx4 = *(const fvec4*)(ddfb + lin0);
    fvec4 dy4 = *(const fvec4*)(ddfb + lin0 + N);
    fvec4 dz4 = *(const fvec4*)(ddfb + lin0 + 2 * N);

    float dxp[4] = {dx4.x, dx4.y, dx4.z, dx4.w};
    float dyp[4] = {dy4.x, dy4.y, dy4.z, dy4.w};
    float dzp[4] = {dz4.x, dz4.y, dz4.z, dz4.w};
    float res[4];

#pragma unroll
    for (int i = 0; i < 4; ++i) {
        float x = (float)vx + dxp[i];
        float y = (float)vy + dyp[i];
        float z = (float)(vz + i) + dzp[i];

        float xf = floorf(x), yf = floorf(y), zf = floorf(z);
        float fx = x - xf, fy = y - yf, fz = z - zf;
        int x0 = (int)xf, y0 = (int)yf, z0 = (int)zf;
        int x1 = x0 + 1, y1 = y0 + 1, z1 = z0 + 1;

        // zeros padding: out-of-range tap => weight 0, index clamped to a
        // safe in-range address (loaded value is multiplied by 0).
        bool bx0 = (unsigned)x0 < (unsigned)H;
        bool bx1 = (unsigned)x1 < (unsigned)H;
        bool by0 = (unsigned)y0 < (unsigned)W;
        bool by1 = (unsigned)y1 < (unsigned)W;
        bool bz0 = (unsigned)z0 < (unsigned)D;
        bool bz1 = (unsigned)z1 < (unsigned)D;
        float ax0 = bx0 ? (1.0f - fx) : 0.0f;
        float ax1 = bx1 ? fx          : 0.0f;
        float ay0 = by0 ? (1.0f - fy) : 0.0f;
        float ay1 = by1 ? fy          : 0.0f;
        float az0 = bz0 ? (1.0f - fz) : 0.0f;
        float az1 = bz1 ? fz          : 0.0f;
        int cx0 = bx0 ? x0 : 0;
        int cx1 = bx1 ? x1 : 0;
        int cy0 = by0 ? y0 : 0;
        int cy1 = by1 ? y1 : 0;
        int cz0 = bz0 ? z0 : 0;
        int cz1 = bz1 ? z1 : 0;

        int rx0 = cx0 << 14, rx1 = cx1 << 14;
        int ry0 = cy0 << 7,  ry1 = cy1 << 7;
        int a00 = rx0 + ry0, a01 = rx0 + ry1;
        int a10 = rx1 + ry0, a11 = rx1 + ry1;

        // 8 independent dword gathers (L1/L2-resident slab); the compiler
        // pipelines all 8 per output and across the 4 outputs.
        float v000 = img[a00 + cz0];
        float v001 = img[a00 + cz1];
        float v010 = img[a01 + cz0];
        float v011 = img[a01 + cz1];
        float v100 = img[a10 + cz0];
        float v101 = img[a10 + cz1];
        float v110 = img[a11 + cz0];
        float v111 = img[a11 + cz1];

        res[i] = ax0 * (ay0 * (az0 * v000 + az1 * v001) +
                        ay1 * (az0 * v010 + az1 * v011)) +
                 ax1 * (ay0 * (az0 * v100 + az1 * v101) +
                        ay1 * (az0 * v110 + az1 * v111));
    }

    float* outb = out + ((size_t)b << 21);
    fvec4 r4 = {res[0], res[1], res[2], res[3]};
    __builtin_nontemporal_store(r4, (fvec4*)(outb + lin0));
}

extern "C" void kernel_launch(void* const* d_in, const int* in_sizes, int n_in,
                              void* d_out, int out_size, void* d_ws, size_t ws_size,
                              hipStream_t stream) {
    const float* image = (const float*)d_in[0];
    const float* ddf   = (const float*)d_in[1];
    float* out = (float*)d_out;

    warp_gather_kernel<<<B * 512, 1024, 0, stream>>>(image, ddf, out);
}

// Round 9
// 102.386 us; speedup vs baseline: 1.5066x; 1.5066x over previous
//
#include <hip/hip_runtime.h>
#include <hip/hip_fp16.h>

// Warp: trilinear grid_sample, padding_mode='zeros', align_corners=true.
// image: (B=2, C=1, H=128, W=128, D=128) fp32
// ddf:   (B=2, 3, H, W, D) fp32 voxel displacements; out: (B,1,H,W,D) fp32
//
// R19 = exact R17/R14 restoration (best measured: 102.5-103.9us).
// Complete ledger (do NOT retry):
//  - R12 LDS 18-cell pad:    null (tap bank conflicts hidden)
//  - R13 nontemporal ddf:    -14us (NT bypasses cache for 50MB stream)
//  - R15 rolling-x 2-tile:   -8.8us (fewer blocks + more barriers lose)
//  - R16 ddf after barrier:  -8.6us (pre-barrier ddf is concurrent with
//    staging loads: barrier drain waits max(latency), not sum)
//  - R18 direct-global gather, no LDS/barrier: kernel 93-100us vs ~34us
//    staged (3x WORSE). Counters: hbm 7.5% peak, VALUBusy 8%, occ 52% ->
//    TA/L1 scattered-load serialization is the wall; LDS staging amortizes
//    exactly that. Structure validated from both directions.
// Structure: 1024 independent one-shot blocks (2/CU antiphase), XCD slab
// swizzle, fp32->fp16 LDS tile (72KB, 18-cell padded rows), pre-barrier ddf,
// z-pair uint2 taps + v_alignbit, setprio(1) compute (T5), rare-path fp32
// global gather, NT fvec4 out store.

constexpr int H = 128, W = 128, D = 128;
constexpr int N = H * W * D;      // 2^21
constexpr int B = 2;
constexpr int HA = 8;             // halo per side
constexpr int RS = 32;            // region edge
constexpr int RCELL = 18;         // padded cells (half2) per row (16 data + 2 pad)
constexpr int RHALF = RCELL * 2;  // halfs per row = 36
constexpr int RN = RS * RS * RHALF;  // 36864 halfs = 72 KB

typedef float fvec4 __attribute__((ext_vector_type(4)));
typedef unsigned u2v __attribute__((ext_vector_type(2), aligned(4)));
typedef unsigned u2v8 __attribute__((ext_vector_type(2), aligned(8)));

__global__ __launch_bounds__(1024, 8) void warp_tile_kernel(
    const float* __restrict__ image,
    const float* __restrict__ ddf,
    float* __restrict__ out)
{
    __shared__ __half tile[RN];   // 72 KB -> 2 blocks/CU

    // XCD slab swizzle: blocks dispatch round-robin over 8 XCDs; give XCD k
    // the contiguous tile range [k*128, (k+1)*128) (= 2 x-slabs, ~2MB image
    // region + halos -> fits that XCD's 4MB L2).
    int bid = blockIdx.x;
    int T   = (bid & 7) * 128 + (bid >> 3);
    int b  = T >> 9;              // 512 tiles per batch
    int t3 = T & 511;
    int tx0 = ((t3 >> 6) & 7) << 4;
    int ty0 = ((t3 >> 3) & 7) << 4;
    int tz0 = (t3 & 7) << 4;
    int ox = tx0 - HA, oy = ty0 - HA, oz = tz0 - HA;

    const float* img = image + ((size_t)b << 21);
    int t = threadIdx.x;          // 0..1023

    // ---- thread -> 4 consecutive z voxels ----
    int zq = (t & 3) << 2;        // 0,4,8,12
    int ly = (t >> 2) & 15;
    int lx = t >> 6;
    int vx = tx0 + lx, vy = ty0 + ly, vz = tz0 + zq;
    int lin0 = (vx << 14) + (vy << 7) + vz;      // 16B aligned

    // ---- stage 32^3 region as fp16 (zeros outside volume) ----
    // 4096 32-byte (8-float) chunks; chunk s: row = s>>2 (rx*32+ry),
    // zo = (s&3)*8. oz = 0 mod 8 -> chunk fully inside or fully outside.
    fvec4 sa[4], sb[4];
    int rows[4], zos[4];
#pragma unroll
    for (int c = 0; c < 4; ++c) {
        int s   = c * 1024 + t;
        int row = s >> 2;
        int zo  = (s & 3) << 3;
        rows[c] = row; zos[c] = zo;
        int gx = ox + (row >> 5);
        int gy = oy + (row & 31);
        int gz = oz + zo;
        bool ok = ((unsigned)gx < 128u) & ((unsigned)gy < 128u) & ((unsigned)gz < 121u);
        const float* p = img + (gx << 14) + (gy << 7) + gz;
        fvec4 z4 = {0.f, 0.f, 0.f, 0.f};
        sa[c] = ok ? *(const fvec4*)p       : z4;
        sb[c] = ok ? *(const fvec4*)(p + 4) : z4;
    }

    // ddf loads: issued pre-barrier, concurrent with the staging loads
    // (barrier drain waits on max latency, not sum -> effectively free).
    const float* ddfb = ddf + (size_t)b * 3 * N;
    fvec4 dx4 = *(const fvec4*)(ddfb + lin0);
    fvec4 dy4 = *(const fvec4*)(ddfb + lin0 + N);
    fvec4 dz4 = *(const fvec4*)(ddfb + lin0 + 2 * N);

    unsigned short* tp = (unsigned short*)tile;
#pragma unroll
    for (int c = 0; c < 4; ++c) {
        __half2 h0 = __floats2half2_rn(sa[c].x, sa[c].y);
        __half2 h1 = __floats2half2_rn(sa[c].z, sa[c].w);
        __half2 h2 = __floats2half2_rn(sb[c].x, sb[c].y);
        __half2 h3 = __floats2half2_rn(sb[c].z, sb[c].w);
        u2v8 w0, w1;
        w0.x = *(unsigned int*)&h0;
        w0.y = *(unsigned int*)&h1;
        w1.x = *(unsigned int*)&h2;
        w1.y = *(unsigned int*)&h3;
        // byte addr = 72*row + 2*zo + {0,8}: always 8B aligned -> ds_write_b64
        unsigned short* dst = tp + rows[c] * RHALF + zos[c];
        *(u2v8*)dst       = w0;
        *(u2v8*)(dst + 4) = w1;
    }
    __syncthreads();

    // Compute phase: boost issue priority. The co-resident block on this CU
    // is (typically) in its staging phase; preferring compute waves retires
    // blocks faster and smooths HBM demand (T5; independent-block regime).
    __builtin_amdgcn_s_setprio(1);

    // ---- compute 4 outputs (consecutive z), one float4 store ----
    float* outb = out + ((size_t)b << 21);
    const unsigned int* cells = (const unsigned int*)tile;   // half2 cells, 4B
    float dxp[4] = {dx4.x, dx4.y, dx4.z, dx4.w};
    float dyp[4] = {dy4.x, dy4.y, dy4.z, dy4.w};
    float dzp[4] = {dz4.x, dz4.y, dz4.z, dz4.w};
    float res[4];

#pragma unroll
    for (int i = 0; i < 4; ++i) {
        float x = (float)vx + dxp[i];
        float y = (float)vy + dyp[i];
        float z = (float)(vz + i) + dzp[i];

        float xf = floorf(x), yf = floorf(y), zf = floorf(z);
        float fx = x - xf, fy = y - yf, fz = z - zf;
        int x0 = (int)xf, y0 = (int)yf, z0 = (int)zf;
        int rx = x0 - ox, ry = y0 - oy, rz = z0 - oz;

        float acc;
        if ((unsigned)rx <= 30u && (unsigned)ry <= 30u && (unsigned)rz <= 30u) {
            // fast path: staged zeros implement zero-padding exactly.
            // z-pair (rz, rz+1) in cells c,c+1 (4B-aligned uint2 ->
            // ds_read2_b32; the straddle is resolved with v_alignbit).
            int row = (rx << 5) + ry;
            int c   = row * RCELL + (rz >> 1);
            int sh  = (rz & 1) << 4;
            u2v q00 = *(const u2v*)(cells + c);
            u2v q01 = *(const u2v*)(cells + c + RCELL);
            u2v q10 = *(const u2v*)(cells + c + 32 * RCELL);
            u2v q11 = *(const u2v*)(cells + c + 33 * RCELL);

            float az0 = 1.f - fz;
            float zz[4];
            unsigned los[4] = {q00.x, q01.x, q10.x, q11.x};
            unsigned his[4] = {q00.y, q01.y, q10.y, q11.y};
#pragma unroll
            for (int p2 = 0; p2 < 4; ++p2) {
                unsigned pr = __builtin_amdgcn_alignbit(his[p2], los[p2],
                                                        (unsigned)sh);
                __half2 hp = *(__half2*)&pr;
                float2 f2 = __half22float2(hp);
                zz[p2] = az0 * f2.x + fz * f2.y;
            }
            float ay0 = 1.f - fy;
            acc = (1.f - fx) * (ay0 * zz[0] + fy * zz[1]) +
                  fx         * (ay0 * zz[2] + fy * zz[3]);
        } else {
            // rare: exact fp32 global gather with zero-padding.
            int x1 = x0 + 1, y1 = y0 + 1, z1 = z0 + 1;
            bool vx0 = (unsigned)x0 < (unsigned)H;
            bool vx1 = (unsigned)x1 < (unsigned)H;
            bool vy0 = (unsigned)y0 < (unsigned)W;
            bool vy1 = (unsigned)y1 < (unsigned)W;
            bool vz0 = (unsigned)z0 < (unsigned)D;
            bool vz1 = (unsigned)z1 < (unsigned)D;
            float ax0 = vx0 ? (1.0f - fx) : 0.0f;
            float ax1 = vx1 ? fx          : 0.0f;
            float ay0 = vy0 ? (1.0f - fy) : 0.0f;
            float ay1 = vy1 ? fy          : 0.0f;
            float az0 = vz0 ? (1.0f - fz) : 0.0f;
            float az1 = vz1 ? fz          : 0.0f;
            int cx0 = vx0 ? x0 : 0;
            int cx1 = vx1 ? x1 : 0;
            int cy0 = vy0 ? y0 : 0;
            int cy1 = vy1 ? y1 : 0;
            int cz0 = vz0 ? z0 : 0;
            int cz1 = vz1 ? z1 : 0;
            int rx0 = cx0 << 14, rx1 = cx1 << 14;
            int ry0 = cy0 << 7,  ry1 = cy1 << 7;
            float v000 = img[rx0 + ry0 + cz0];
            float v001 = img[rx0 + ry0 + cz1];
            float v010 = img[rx0 + ry1 + cz0];
            float v011 = img[rx0 + ry1 + cz1];
            float v100 = img[rx1 + ry0 + cz0];
            float v101 = img[rx1 + ry0 + cz1];
            float v110 = img[rx1 + ry1 + cz0];
            float v111 = img[rx1 + ry1 + cz1];
            acc = ax0 * (ay0 * (az0 * v000 + az1 * v001) +
                         ay1 * (az0 * v010 + az1 * v011)) +
                  ax1 * (ay0 * (az0 * v100 + az1 * v101) +
                         ay1 * (az0 * v110 + az1 * v111));
        }
        res[i] = acc;
    }
    __builtin_amdgcn_s_setprio(0);
    fvec4 r4 = {res[0], res[1], res[2], res[3]};
    __builtin_nontemporal_store(r4, (fvec4*)(outb + lin0));
}

extern "C" void kernel_launch(void* const* d_in, const int* in_sizes, int n_in,
                              void* d_out, int out_size, void* d_ws, size_t ws_size,
                              hipStream_t stream) {
    const float* image = (const float*)d_in[0];
    const float* ddf   = (const float*)d_in[1];
    float* out = (float*)d_out;

    warp_tile_kernel<<<B * 512, 1024, 0, stream>>>(image, ddf, out);
}